// Round 1
// baseline (185.028 us; speedup 1.0000x reference)
//
#include <hip/hip_runtime.h>
#include <math.h>

#define BATCH 4096
#define W 4096
#define POS_NUM 10
#define NUM_NEG 30
#define SEL_PER_ROW 40   // 10 pos + 30 neg
#define TPB 256
#define EPT (W / TPB)    // 16

// ---------------- Kernel A: per-batch 3x3 work in double ----------------
__global__ __launch_bounds__(TPB) void mat_kernel(
    const float* __restrict__ gt_T, const float* __restrict__ gt_e,
    const float* __restrict__ pred_e, int* __restrict__ xmin_out,
    float* __restrict__ fl_out) {
  int b = blockIdx.x * TPB + threadIdx.x;
  if (b >= BATCH) return;
  const float* T = gt_T + (size_t)b * 16;
  const float* E = gt_e + (size_t)b * 16;
  const float* P = pred_e + (size_t)b * 16;
  double r[9], e[9], p[9];
  #pragma unroll
  for (int i = 0; i < 3; ++i)
    #pragma unroll
    for (int j = 0; j < 3; ++j) {
      r[i * 3 + j] = (double)T[i * 4 + j];
      e[i * 3 + j] = (double)E[i * 4 + j];
      p[i * 3 + j] = (double)P[i * 4 + j];
    }
  // inv(r) via adjugate
  double inv[9];
  {
    double a = r[0], bb = r[1], c = r[2], d = r[3], ee = r[4], f = r[5],
           g = r[6], h = r[7], ii = r[8];
    double A = ee * ii - f * h, Bc = f * g - d * ii, C = d * h - ee * g;
    double det = a * A + bb * Bc + c * C;
    double idet = 1.0 / det;
    inv[0] = A * idet;  inv[1] = (c * h - bb * ii) * idet; inv[2] = (bb * f - c * ee) * idet;
    inv[3] = Bc * idet; inv[4] = (a * ii - c * g) * idet;  inv[5] = (c * d - a * f) * idet;
    inv[6] = C * idet;  inv[7] = (bb * g - a * h) * idet;  inv[8] = (a * ee - bb * d) * idet;
  }
  // axis = pred33 @ inv[:,0]
  double ax = p[0] * inv[0] + p[1] * inv[3] + p[2] * inv[6];
  double ay = p[3] * inv[0] + p[4] * inv[3] + p[5] * inv[6];
  double yaw = atan2(ay, ax);
  double fidx = (-yaw + M_PI) / (2.0 * M_PI) * (double)W;
  xmin_out[b] = (int)fidx - POS_NUM / 2;

  // m = gt_e33 @ inv ; R33 = inv(m)
  double m[9];
  #pragma unroll
  for (int i = 0; i < 3; ++i)
    #pragma unroll
    for (int j = 0; j < 3; ++j)
      m[i * 3 + j] = e[i * 3 + 0] * inv[0 * 3 + j] + e[i * 3 + 1] * inv[1 * 3 + j] +
                     e[i * 3 + 2] * inv[2 * 3 + j];
  double R[9];
  {
    double a = m[0], bb = m[1], c = m[2], d = m[3], ee = m[4], f = m[5],
           g = m[6], h = m[7], ii = m[8];
    double A = ee * ii - f * h, Bc = f * g - d * ii, C = d * h - ee * g;
    double det = a * A + bb * Bc + c * C;
    double idet = 1.0 / det;
    R[0] = A * idet;  R[1] = (c * h - bb * ii) * idet; R[2] = (bb * f - c * ee) * idet;
    R[3] = Bc * idet; R[4] = (a * ii - c * g) * idet;  R[5] = (c * d - a * f) * idet;
    R[6] = C * idet;  R[7] = (bb * g - a * h) * idet;  R[8] = (a * ee - bb * d) * idet;
  }
  float* fl = fl_out + (size_t)b * 16;
  fl[0] = (float)R[0]; fl[1] = (float)R[1]; fl[2]  = (float)R[2]; fl[3]  = 0.f;
  fl[4] = (float)R[3]; fl[5] = (float)R[4]; fl[6]  = (float)R[5]; fl[7]  = 0.f;
  fl[8] = (float)R[6]; fl[9] = (float)R[7]; fl[10] = (float)R[8]; fl[11] = 0.f;
  fl[12] = 0.f; fl[13] = 0.f; fl[14] = 0.f; fl[15] = 1.f;
}

// ---------------- Kernel B: per-row BCE + top-30 sum via radix select ----------------
__global__ __launch_bounds__(TPB) void row_kernel(
    const float* __restrict__ pred, const int* __restrict__ xmin_arr,
    float* __restrict__ gt_out, float* __restrict__ row_sum) {
  int b = blockIdx.x;
  int tid = threadIdx.x;
  __shared__ float vals[W];
  __shared__ unsigned hist[TPB];
  __shared__ unsigned cnt_ge[TPB];
  __shared__ int s_bucket;
  __shared__ unsigned s_need;
  __shared__ float red_s[4];
  __shared__ int red_c[4];

  int xmin = xmin_arr[b];
  const float* prow = pred + (size_t)b * W;
  float* grow = gt_out + (size_t)b * W;

  float pos_sum = 0.0f;
  #pragma unroll
  for (int k = 0; k < EPT; ++k) {
    int w = tid + k * TPB;
    float p = prow[w];
    bool pos = (((w - xmin) & (W - 1)) < POS_NUM);
    grow[w] = pos ? 1.0f : 0.0f;
    float v = 0.0f;
    if (pos) {
      pos_sum += fminf(-logf(p), 100.0f);       // BCE for y=1
    } else {
      v = fminf(-log1pf(-p), 100.0f);           // BCE for y=0 (candidate neg)
    }
    vals[w] = v;                                 // positives stored as 0 -> never top-30
  }
  __syncthreads();

  // radix select: find the 30th largest value (float bits, all >= 0)
  unsigned need = NUM_NEG;
  unsigned prefix = 0;
  for (int shift = 24; shift >= 0; shift -= 8) {
    hist[tid] = 0;
    __syncthreads();
    unsigned mask_hi = (shift == 24) ? 0u : (0xFFFFFFFFu << (shift + 8));
    #pragma unroll
    for (int k = 0; k < EPT; ++k) {
      unsigned key = __float_as_uint(vals[tid + k * TPB]);
      if ((key & mask_hi) == prefix)
        atomicAdd(&hist[(key >> shift) & 0xFFu], 1u);
    }
    __syncthreads();
    cnt_ge[tid] = hist[tid];
    __syncthreads();
    // suffix sum: cnt_ge[t] = count of keys with byte >= t
    for (int off = 1; off < TPB; off <<= 1) {
      unsigned add = (tid + off < TPB) ? cnt_ge[tid + off] : 0u;
      __syncthreads();
      cnt_ge[tid] += add;
      __syncthreads();
    }
    unsigned ge = cnt_ge[tid];
    unsigned ge_next = (tid < TPB - 1) ? cnt_ge[tid + 1] : 0u;
    if (ge >= need && ge_next < need) {  // exactly one thread (monotone)
      s_bucket = tid;
      s_need = need - ge_next;
    }
    __syncthreads();
    prefix |= ((unsigned)s_bucket) << shift;
    need = s_need;
    __syncthreads();
  }
  float t = __uint_as_float(prefix);  // exact 30th-largest value

  // sum of strictly-greater values + count; ties contribute t each
  float gsum = 0.0f;
  int gcnt = 0;
  #pragma unroll
  for (int k = 0; k < EPT; ++k) {
    float v = vals[tid + k * TPB];
    if (v > t) { gsum += v; gcnt++; }
  }
  float s = pos_sum + gsum;
  int c = gcnt;
  #pragma unroll
  for (int off = 32; off >= 1; off >>= 1) {
    s += __shfl_xor(s, off);
    c += __shfl_xor(c, off);
  }
  int wid = tid >> 6, lane = tid & 63;
  if (lane == 0) { red_s[wid] = s; red_c[wid] = c; }
  __syncthreads();
  if (tid == 0) {
    float S = red_s[0] + red_s[1] + red_s[2] + red_s[3];
    int C = red_c[0] + red_c[1] + red_c[2] + red_c[3];
    row_sum[b] = S + ((float)NUM_NEG - (float)C) * t;
  }
}

// ---------------- Kernel C: final reduction ----------------
__global__ __launch_bounds__(TPB) void reduce_kernel(
    const float* __restrict__ row_sum, float* __restrict__ out) {
  int tid = threadIdx.x;
  double acc = 0.0;
  for (int i = tid; i < BATCH; i += TPB) acc += (double)row_sum[i];
  #pragma unroll
  for (int off = 32; off >= 1; off >>= 1) acc += __shfl_xor(acc, off);
  __shared__ double sh[4];
  int wid = tid >> 6, lane = tid & 63;
  if (lane == 0) sh[wid] = acc;
  __syncthreads();
  if (tid == 0) {
    double total = sh[0] + sh[1] + sh[2] + sh[3];
    out[0] = (float)(total / (double)((size_t)SEL_PER_ROW * BATCH));
  }
}

extern "C" void kernel_launch(void* const* d_in, const int* in_sizes, int n_in,
                              void* d_out, int out_size, void* d_ws, size_t ws_size,
                              hipStream_t stream) {
  const float* gt_T   = (const float*)d_in[0];
  const float* gt_e   = (const float*)d_in[1];
  const float* pred_e = (const float*)d_in[2];
  const float* pred_f = (const float*)d_in[3];
  float* out = (float*)d_out;
  float* gt_score = out + 1;
  float* fl = out + 1 + (size_t)BATCH * W;
  int* xmin_ws = (int*)d_ws;
  float* row_sum = (float*)d_ws + BATCH;

  mat_kernel<<<BATCH / TPB, TPB, 0, stream>>>(gt_T, gt_e, pred_e, xmin_ws, fl);
  row_kernel<<<BATCH, TPB, 0, stream>>>(pred_f, xmin_ws, gt_score, row_sum);
  reduce_kernel<<<1, TPB, 0, stream>>>(row_sum, out);
}

// Round 2
// 169.331 us; speedup vs baseline: 1.0927x; 1.0927x over previous
//
#include <hip/hip_runtime.h>
#include <math.h>

#define BATCH 4096
#define W 4096
#define POS_NUM 10
#define NUM_NEG 30
#define SEL_PER_ROW 40   // 10 pos + 30 neg
#define TPB 256

__device__ __forceinline__ void inv3x3(const double* m, double* inv) {
  double a = m[0], b = m[1], c = m[2], d = m[3], e = m[4], f = m[5],
         g = m[6], h = m[7], i = m[8];
  double A = e * i - f * h, B = f * g - d * i, C = d * h - e * g;
  double det = a * A + b * B + c * C;
  double id = 1.0 / det;
  inv[0] = A * id; inv[1] = (c * h - b * i) * id; inv[2] = (b * f - c * e) * id;
  inv[3] = B * id; inv[4] = (a * i - c * g) * id; inv[5] = (c * d - a * f) * id;
  inv[6] = C * id; inv[7] = (b * g - a * h) * id; inv[8] = (a * e - b * d) * id;
}

// One block per row: fused per-row f64 matrix chain + BCE + gt write + top-30 sum.
__global__ __launch_bounds__(TPB) void row_kernel(
    const float* __restrict__ gt_T, const float* __restrict__ gt_e,
    const float* __restrict__ pred_e, const float* __restrict__ pred,
    float* __restrict__ gt_out, float* __restrict__ fl_out,
    float* __restrict__ row_sum) {
  int b = blockIdx.x;
  int tid = threadIdx.x;
  __shared__ float cand[W];          // worst-case capacity (fallback path)
  __shared__ unsigned s_cnt;
  __shared__ int s_xmin;
  __shared__ float s_pos[TPB / 64];
  if (tid == 0) s_cnt = 0;

  // issue the row loads early; latency overlaps thread 0's f64 chain
  const float4* prow = (const float4*)(pred + (size_t)b * W);
  float4 pv[4];
  #pragma unroll
  for (int k = 0; k < 4; ++k) pv[k] = prow[tid + k * TPB];

  if (tid == 0) {
    const float* T = gt_T + (size_t)b * 16;
    const float* E = gt_e + (size_t)b * 16;
    const float* P = pred_e + (size_t)b * 16;
    double r[9], e[9], p[9];
    #pragma unroll
    for (int i = 0; i < 3; ++i)
      #pragma unroll
      for (int j = 0; j < 3; ++j) {
        r[i * 3 + j] = (double)T[i * 4 + j];
        e[i * 3 + j] = (double)E[i * 4 + j];
        p[i * 3 + j] = (double)P[i * 4 + j];
      }
    double rinv[9];
    inv3x3(r, rinv);
    double ax = p[0] * rinv[0] + p[1] * rinv[3] + p[2] * rinv[6];
    double ay = p[3] * rinv[0] + p[4] * rinv[3] + p[5] * rinv[6];
    double yaw = atan2(ay, ax);
    double fidx = (-yaw + M_PI) / (2.0 * M_PI) * (double)W;
    s_xmin = (int)fidx - POS_NUM / 2;

    double m[9];
    #pragma unroll
    for (int i = 0; i < 3; ++i)
      #pragma unroll
      for (int j = 0; j < 3; ++j)
        m[i * 3 + j] = e[i * 3 + 0] * rinv[0 * 3 + j] +
                       e[i * 3 + 1] * rinv[1 * 3 + j] +
                       e[i * 3 + 2] * rinv[2 * 3 + j];
    double R[9];
    inv3x3(m, R);
    float* fl = fl_out + (size_t)b * 16;
    fl[0] = (float)R[0]; fl[1] = (float)R[1]; fl[2]  = (float)R[2]; fl[3]  = 0.f;
    fl[4] = (float)R[3]; fl[5] = (float)R[4]; fl[6]  = (float)R[5]; fl[7]  = 0.f;
    fl[8] = (float)R[6]; fl[9] = (float)R[7]; fl[10] = (float)R[8]; fl[11] = 0.f;
    fl[12] = 0.f; fl[13] = 0.f; fl[14] = 0.f; fl[15] = 1.f;
  }
  __syncthreads();          // xmin + s_cnt=0 visible
  int xmin = s_xmin;

  float4* grow = (float4*)(gt_out + (size_t)b * W);
  float v[16];
  float pos_sum = 0.f;
  #pragma unroll
  for (int k = 0; k < 4; ++k) {
    int vec = tid + k * TPB;
    float pe0 = pv[k].x, pe1 = pv[k].y, pe2 = pv[k].z, pe3 = pv[k].w;
    int w0 = vec * 4;
    bool q0 = (((w0 + 0 - xmin) & (W - 1)) < POS_NUM);
    bool q1 = (((w0 + 1 - xmin) & (W - 1)) < POS_NUM);
    bool q2 = (((w0 + 2 - xmin) & (W - 1)) < POS_NUM);
    bool q3 = (((w0 + 3 - xmin) & (W - 1)) < POS_NUM);
    float4 g;
    g.x = q0 ? 1.f : 0.f; g.y = q1 ? 1.f : 0.f;
    g.z = q2 ? 1.f : 0.f; g.w = q3 ? 1.f : 0.f;
    grow[vec] = g;
    if (q0) { pos_sum += fminf(-logf(pe0), 100.f); v[k * 4 + 0] = -3.f; }
    else    { v[k * 4 + 0] = fminf(-log1pf(-pe0), 100.f); }
    if (q1) { pos_sum += fminf(-logf(pe1), 100.f); v[k * 4 + 1] = -3.f; }
    else    { v[k * 4 + 1] = fminf(-log1pf(-pe1), 100.f); }
    if (q2) { pos_sum += fminf(-logf(pe2), 100.f); v[k * 4 + 2] = -3.f; }
    else    { v[k * 4 + 2] = fminf(-log1pf(-pe2), 100.f); }
    if (q3) { pos_sum += fminf(-logf(pe3), 100.f); v[k * 4 + 3] = -3.f; }
    else    { v[k * 4 + 3] = fminf(-log1pf(-pe3), 100.f); }
  }

  // candidate filter with deterministic widening fallback (fast path: 1 pass)
  float thi = 1e30f;
  float tlo = 4.0f;
  while (true) {
    int loc = 0;
    #pragma unroll
    for (int j = 0; j < 16; ++j) loc += ((v[j] > tlo) && (v[j] <= thi)) ? 1 : 0;
    if (loc) {
      unsigned base = atomicAdd(&s_cnt, (unsigned)loc);
      #pragma unroll
      for (int j = 0; j < 16; ++j)
        if ((v[j] > tlo) && (v[j] <= thi)) cand[base++] = v[j];
    }
    __syncthreads();                       // appends + s_cnt visible
    if (s_cnt >= NUM_NEG || tlo <= -0.5f) break;  // uniform decision
    thi = tlo;
    tlo = (tlo > 2.0f) ? (tlo - 2.0f) : -1.0f;    // -1 captures all negatives (v > 0)
    __syncthreads();                       // protect s_cnt read vs next append
  }

  // block-reduce pos_sum
  float s = pos_sum;
  #pragma unroll
  for (int off = 32; off >= 1; off >>= 1) s += __shfl_xor(s, off);
  if ((tid & 63) == 0) s_pos[tid >> 6] = s;
  __syncthreads();

  // wave 0: exact stable-rank top-30 sum over C candidates (broadcast reads)
  if (tid < 64) {
    unsigned C = s_cnt;
    float tsum = 0.f;
    for (unsigned base0 = 0; base0 < C; base0 += 64) {
      unsigned myi = base0 + (unsigned)tid;
      bool valid = (myi < C);
      float mine = valid ? cand[myi] : -1.f;
      int rank = valid ? 0 : NUM_NEG;
      for (unsigned j = 0; j < C; ++j) {
        float cj = cand[j];
        rank += ((cj > mine) || (cj == mine && j < myi)) ? 1 : 0;
      }
      if (rank < NUM_NEG) tsum += mine;
    }
    #pragma unroll
    for (int off = 32; off >= 1; off >>= 1) tsum += __shfl_xor(tsum, off);
    if (tid == 0)
      row_sum[b] = tsum + s_pos[0] + s_pos[1] + s_pos[2] + s_pos[3];
  }
}

__global__ __launch_bounds__(TPB) void reduce_kernel(
    const float* __restrict__ row_sum, float* __restrict__ out) {
  int tid = threadIdx.x;
  double acc = 0.0;
  for (int i = tid; i < BATCH; i += TPB) acc += (double)row_sum[i];
  #pragma unroll
  for (int off = 32; off >= 1; off >>= 1) acc += __shfl_xor(acc, off);
  __shared__ double sh[4];
  int wid = tid >> 6, lane = tid & 63;
  if (lane == 0) sh[wid] = acc;
  __syncthreads();
  if (tid == 0) {
    double total = sh[0] + sh[1] + sh[2] + sh[3];
    out[0] = (float)(total / (double)((size_t)SEL_PER_ROW * BATCH));
  }
}

extern "C" void kernel_launch(void* const* d_in, const int* in_sizes, int n_in,
                              void* d_out, int out_size, void* d_ws, size_t ws_size,
                              hipStream_t stream) {
  const float* gt_T   = (const float*)d_in[0];
  const float* gt_e   = (const float*)d_in[1];
  const float* pred_e = (const float*)d_in[2];
  const float* pred_f = (const float*)d_in[3];
  float* out = (float*)d_out;
  float* gt_score = out + 1;
  float* fl = out + 1 + (size_t)BATCH * W;
  float* row_sum = (float*)d_ws;

  row_kernel<<<BATCH, TPB, 0, stream>>>(gt_T, gt_e, pred_e, pred_f,
                                        gt_score, fl, row_sum);
  reduce_kernel<<<1, TPB, 0, stream>>>(row_sum, out);
}

// Round 3
// 132.756 us; speedup vs baseline: 1.3937x; 1.2755x over previous
//
#include <hip/hip_runtime.h>
#include <math.h>

#define BATCH 4096
#define W 4096
#define POS_NUM 10
#define NUM_NEG 30
#define SEL_PER_ROW 40   // 10 pos + 30 neg
#define TPB 256

__device__ __forceinline__ void inv3x3(const double* m, double* inv) {
  double a = m[0], b = m[1], c = m[2], d = m[3], e = m[4], f = m[5],
         g = m[6], h = m[7], i = m[8];
  double A = e * i - f * h, B = f * g - d * i, C = d * h - e * g;
  double det = a * A + b * B + c * C;
  double id = 1.0 / det;
  inv[0] = A * id; inv[1] = (c * h - b * i) * id; inv[2] = (b * f - c * e) * id;
  inv[3] = B * id; inv[4] = (a * i - c * g) * id; inv[5] = (c * d - a * f) * id;
  inv[6] = C * id; inv[7] = (b * g - a * h) * id; inv[8] = (a * e - b * d) * id;
}

// One block per row. Selection is done on RAW p (monotone in BCE value);
// logs are computed only for the <=30 selected negatives and ~10 positives.
__global__ __launch_bounds__(TPB) void row_kernel(
    const float* __restrict__ gt_T, const float* __restrict__ gt_e,
    const float* __restrict__ pred_e, const float* __restrict__ pred,
    float* __restrict__ gt_out, float* __restrict__ fl_out,
    float* __restrict__ row_sum) {
  int b = blockIdx.x;
  int tid = threadIdx.x;
  __shared__ float cand[W];          // capacity for the (never-taken) full fallback
  __shared__ unsigned s_cnt;
  __shared__ int s_xmin;
  __shared__ float s_pos[TPB / 64];
  if (tid == 0) s_cnt = 0;

  // issue the row loads early; latency overlaps thread 0's f64 chain
  const float4* prow = (const float4*)(pred + (size_t)b * W);
  float4 pv[4];
  #pragma unroll
  for (int k = 0; k < 4; ++k) pv[k] = prow[tid + k * TPB];

  if (tid == 0) {
    const float* T = gt_T + (size_t)b * 16;
    const float* E = gt_e + (size_t)b * 16;
    const float* P = pred_e + (size_t)b * 16;
    double r[9], e[9], p[9];
    #pragma unroll
    for (int i = 0; i < 3; ++i)
      #pragma unroll
      for (int j = 0; j < 3; ++j) {
        r[i * 3 + j] = (double)T[i * 4 + j];
        e[i * 3 + j] = (double)E[i * 4 + j];
        p[i * 3 + j] = (double)P[i * 4 + j];
      }
    double rinv[9];
    inv3x3(r, rinv);
    double ax = p[0] * rinv[0] + p[1] * rinv[3] + p[2] * rinv[6];
    double ay = p[3] * rinv[0] + p[4] * rinv[3] + p[5] * rinv[6];
    double yaw = atan2(ay, ax);
    double fidx = (-yaw + M_PI) / (2.0 * M_PI) * (double)W;
    s_xmin = (int)fidx - POS_NUM / 2;

    double m[9];
    #pragma unroll
    for (int i = 0; i < 3; ++i)
      #pragma unroll
      for (int j = 0; j < 3; ++j)
        m[i * 3 + j] = e[i * 3 + 0] * rinv[0 * 3 + j] +
                       e[i * 3 + 1] * rinv[1 * 3 + j] +
                       e[i * 3 + 2] * rinv[2 * 3 + j];
    double R[9];
    inv3x3(m, R);
    float* fl = fl_out + (size_t)b * 16;
    fl[0] = (float)R[0]; fl[1] = (float)R[1]; fl[2]  = (float)R[2]; fl[3]  = 0.f;
    fl[4] = (float)R[3]; fl[5] = (float)R[4]; fl[6]  = (float)R[5]; fl[7]  = 0.f;
    fl[8] = (float)R[6]; fl[9] = (float)R[7]; fl[10] = (float)R[8]; fl[11] = 0.f;
    fl[12] = 0.f; fl[13] = 0.f; fl[14] = 0.f; fl[15] = 1.f;
  }
  __syncthreads();          // xmin + s_cnt=0 visible
  int xmin = s_xmin;

  float4* grow = (float4*)(gt_out + (size_t)b * W);
  float pp[16];             // raw p; positives overwritten with -3 (never selected)
  float pos_sum = 0.f;
  #pragma unroll
  for (int k = 0; k < 4; ++k) {
    int w0 = (tid + k * TPB) * 4;
    pp[k * 4 + 0] = pv[k].x; pp[k * 4 + 1] = pv[k].y;
    pp[k * 4 + 2] = pv[k].z; pp[k * 4 + 3] = pv[k].w;
    float4 g;
    float* gc = (float*)&g;
    #pragma unroll
    for (int j = 0; j < 4; ++j) {
      bool q = (((w0 + j - xmin) & (W - 1)) < POS_NUM);
      gc[j] = q ? 1.f : 0.f;
      if (q) {
        pos_sum += fminf(-logf(pp[k * 4 + j]), 100.f);
        pp[k * 4 + j] = -3.f;
      }
    }
    grow[tid + k * TPB] = g;
  }

  // candidate filter on raw p with deterministic widening fallback
  float thi = 1e30f;
  float tlo = 0.9865f;
  while (true) {
    int loc = 0;
    #pragma unroll
    for (int j = 0; j < 16; ++j) loc += ((pp[j] > tlo) && (pp[j] <= thi)) ? 1 : 0;
    if (loc) {
      unsigned base = atomicAdd(&s_cnt, (unsigned)loc);
      #pragma unroll
      for (int j = 0; j < 16; ++j)
        if ((pp[j] > tlo) && (pp[j] <= thi)) cand[base++] = pp[j];
    }
    __syncthreads();                       // appends + s_cnt visible
    if (s_cnt >= NUM_NEG || tlo <= -0.5f) break;  // uniform decision
    thi = tlo;
    tlo = (tlo > 0.9f) ? 0.9f : -1.0f;     // -1 captures all negatives (p>0 > -1)
    __syncthreads();                       // protect s_cnt read vs next append
  }

  // block-reduce pos_sum
  float s = pos_sum;
  #pragma unroll
  for (int off = 32; off >= 1; off >>= 1) s += __shfl_xor(s, off);
  if ((tid & 63) == 0) s_pos[tid >> 6] = s;
  __syncthreads();

  // wave 0: exact stable-rank top-30 over candidates (by raw p), then logs
  if (tid < 64) {
    unsigned C = s_cnt;
    float tsum = 0.f;
    for (unsigned base0 = 0; base0 < C; base0 += 64) {
      unsigned myi = base0 + (unsigned)tid;
      bool valid = (myi < C);
      float mine = valid ? cand[myi] : -1.f;
      int rank = valid ? 0 : NUM_NEG;
      for (unsigned j = 0; j < C; ++j) {
        float cj = cand[j];
        rank += ((cj > mine) || (cj == mine && j < myi)) ? 1 : 0;
      }
      if (rank < NUM_NEG) tsum += fminf(-log1pf(-mine), 100.f);
    }
    #pragma unroll
    for (int off = 32; off >= 1; off >>= 1) tsum += __shfl_xor(tsum, off);
    if (tid == 0)
      row_sum[b] = tsum + s_pos[0] + s_pos[1] + s_pos[2] + s_pos[3];
  }
}

__global__ __launch_bounds__(TPB) void reduce_kernel(
    const float* __restrict__ row_sum, float* __restrict__ out) {
  int tid = threadIdx.x;
  double acc = 0.0;
  for (int i = tid; i < BATCH; i += TPB) acc += (double)row_sum[i];
  #pragma unroll
  for (int off = 32; off >= 1; off >>= 1) acc += __shfl_xor(acc, off);
  __shared__ double sh[4];
  int wid = tid >> 6, lane = tid & 63;
  if (lane == 0) sh[wid] = acc;
  __syncthreads();
  if (tid == 0) {
    double total = sh[0] + sh[1] + sh[2] + sh[3];
    out[0] = (float)(total / (double)((size_t)SEL_PER_ROW * BATCH));
  }
}

extern "C" void kernel_launch(void* const* d_in, const int* in_sizes, int n_in,
                              void* d_out, int out_size, void* d_ws, size_t ws_size,
                              hipStream_t stream) {
  const float* gt_T   = (const float*)d_in[0];
  const float* gt_e   = (const float*)d_in[1];
  const float* pred_e = (const float*)d_in[2];
  const float* pred_f = (const float*)d_in[3];
  float* out = (float*)d_out;
  float* gt_score = out + 1;
  float* fl = out + 1 + (size_t)BATCH * W;
  float* row_sum = (float*)d_ws;

  row_kernel<<<BATCH, TPB, 0, stream>>>(gt_T, gt_e, pred_e, pred_f,
                                        gt_score, fl, row_sum);
  reduce_kernel<<<1, TPB, 0, stream>>>(row_sum, out);
}